// Round 3
// baseline (272.052 us; speedup 1.0000x reference)
//
#include <hip/hip_runtime.h>

#define BATCH   8192
#define FBINS   2048
#define KSLOTS  6

#define HBLOCKS 4096
#define HTHREADS 256
#define HSTRIDE (HBLOCKS * HTHREADS)            // 1048576 float4
#define HITERS  4                                // 4096*256*4 = 4194304 = BATCH*FBINS/4

#define RTHREADS 256
#define RBLOCKS (BATCH / RTHREADS)   // 32

#define LS   0.1f
#define LBW  0.05f
#define BWMAX 4.0f
#define LAP  0.5f
#define LPK  0.3f
#define LUM  0.1f

__device__ __forceinline__ float huber4(float4 a, float4 b) {
    float s = 0.f;
    { float e = a.x - b.x; float ab = fabsf(e); s += (ab < 1.f) ? 0.5f * e * e : ab - 0.5f; }
    { float e = a.y - b.y; float ab = fabsf(e); s += (ab < 1.f) ? 0.5f * e * e : ab - 0.5f; }
    { float e = a.z - b.z; float ab = fabsf(e); s += (ab < 1.f) ? 0.5f * e * e : ab - 0.5f; }
    { float e = a.w - b.w; float ab = fabsf(e); s += (ab < 1.f) ? 0.5f * e * e : ab - 0.5f; }
    return s;
}

// ---------------- Kernel 1: per-row greedy matching + small sums ----------------
// rpart layout: rpart[7 * blockIdx + c]:
//   0 amps_sum, 1 bw_sum, 2 ap_sum, 3 peaks_sum, 4 mask_sum, 5 um_cnt, 6 um_amps
__global__ __launch_bounds__(RTHREADS) void row_partial(
    const float* __restrict__ cfs,   const float* __restrict__ amps,
    const float* __restrict__ bws,   const float* __restrict__ expn,
    const float* __restrict__ offs,  const float* __restrict__ gt_cfs,
    const float* __restrict__ gt_amps, const float* __restrict__ gt_bws,
    const float* __restrict__ gt_off, const float* __restrict__ gt_exp,
    const float* __restrict__ mask,  float* __restrict__ rpart)
{
    int b = blockIdx.x * blockDim.x + threadIdx.x;

    float amps_sum = 0.f, bw_sum = 0.f, ap_sum = 0.f, peaks_sum = 0.f;
    float mask_sum = 0.f, um_cnt = 0.f, um_amps = 0.f;

    if (b < BATCH) {
        float c[KSLOTS], a[KSLOTS], w[KSLOTS];
        float gc[KSLOTS], ga[KSLOTS], gw[KSLOTS], m[KSLOTS];
        #pragma unroll
        for (int i = 0; i < KSLOTS; i++) {
            c[i]  = cfs[b * KSLOTS + i];
            a[i]  = amps[b * KSLOTS + i];
            w[i]  = bws[b * KSLOTS + i];
            gc[i] = gt_cfs[b * KSLOTS + i];
            ga[i] = gt_amps[b * KSLOTS + i];
            gw[i] = gt_bws[b * KSLOTS + i];
            m[i]  = mask[b * KSLOTS + i];
        }

        bool used[KSLOTS];
        #pragma unroll
        for (int i = 0; i < KSLOTS; i++) used[i] = false;

        // Sequential greedy over GT slots (lax.scan order); strict < = first-min
        // tie-break, matching jnp.argmin.
        for (int j = 0; j < KSLOTS; j++) {
            if (m[j] > 0.5f) {
                int best = -1;
                float bd = 3.402823e+38f;
                #pragma unroll
                for (int i = 0; i < KSLOTS; i++) {
                    if (!used[i]) {
                        float d = fabsf(gc[j] - c[i]);
                        if (d < bd) { bd = d; best = i; }
                    }
                }
                used[best] = true;
                float dc = c[best] - gc[j];
                float da = a[best] - ga[j];
                float dw = w[best] - gw[j];
                peaks_sum += dc * dc + da * da + dw * dw;
                mask_sum  += 1.f;
            }
        }

        #pragma unroll
        for (int i = 0; i < KSLOTS; i++) {
            amps_sum += a[i];
            float ex = fmaxf(w[i] - BWMAX, 0.f);
            bw_sum += ex * ex;
            if (!used[i]) { um_cnt += 1.f; um_amps += a[i]; }
        }

        float de = expn[b] - gt_exp[b];
        float dof = offs[b] - gt_off[b];
        ap_sum = de * de + dof * dof;
    }

    __shared__ float sm[7][RTHREADS];
    sm[0][threadIdx.x] = amps_sum;
    sm[1][threadIdx.x] = bw_sum;
    sm[2][threadIdx.x] = ap_sum;
    sm[3][threadIdx.x] = peaks_sum;
    sm[4][threadIdx.x] = mask_sum;
    sm[5][threadIdx.x] = um_cnt;
    sm[6][threadIdx.x] = um_amps;
    __syncthreads();
    for (int o = RTHREADS / 2; o > 0; o >>= 1) {
        if (threadIdx.x < o) {
            #pragma unroll
            for (int cidx = 0; cidx < 7; cidx++)
                sm[cidx][threadIdx.x] += sm[cidx][threadIdx.x + o];
        }
        __syncthreads();
    }
    if (threadIdx.x < 7) rpart[7 * blockIdx.x + threadIdx.x] = sm[threadIdx.x][0];
}

// ---------------- Kernel 2: Huber partials + last-block finalize ----------------
__global__ __launch_bounds__(HTHREADS) void huber_main(
    const float* __restrict__ pred, const float* __restrict__ tgt,
    float* __restrict__ hpart,          // HBLOCKS floats
    float* __restrict__ rpart,          // 7*RBLOCKS floats (from row_partial)
    unsigned int* __restrict__ counter, // zeroed via hipMemsetAsync each call
    float* __restrict__ out)
{
    const int tid0 = blockIdx.x * HTHREADS + threadIdx.x;
    const float4* __restrict__ p4 = (const float4*)pred;
    const float4* __restrict__ t4 = (const float4*)tgt;

    // 8 loads issued back-to-back; sched_barrier(0) pins them above the
    // compute so all 128 B/thread stay in flight (MLP).
    float4 a0 = p4[tid0];
    float4 b0 = t4[tid0];
    float4 a1 = p4[tid0 + HSTRIDE];
    float4 b1 = t4[tid0 + HSTRIDE];
    float4 a2 = p4[tid0 + 2 * HSTRIDE];
    float4 b2 = t4[tid0 + 2 * HSTRIDE];
    float4 a3 = p4[tid0 + 3 * HSTRIDE];
    float4 b3 = t4[tid0 + 3 * HSTRIDE];
    __builtin_amdgcn_sched_barrier(0);

    float s = huber4(a0, b0);
    s += huber4(a1, b1);
    s += huber4(a2, b2);
    s += huber4(a3, b3);

    // wave64 shuffle reduce, then cross-wave via LDS
    #pragma unroll
    for (int o = 32; o > 0; o >>= 1)
        s += __shfl_down(s, o, 64);

    __shared__ float wsum[HTHREADS / 64];
    int wave = threadIdx.x >> 6;
    int lane = threadIdx.x & 63;
    if (lane == 0) wsum[wave] = s;
    __syncthreads();

    if (threadIdx.x == 0)
        hpart[blockIdx.x] = wsum[0] + wsum[1] + wsum[2] + wsum[3];

    // ---- completion protocol (last block finalizes) ----
    __shared__ unsigned int lastFlag;
    if (threadIdx.x == 0) {
        __threadfence();  // make hpart[blockIdx.x] visible at device scope
        unsigned int prev = __hip_atomic_fetch_add(counter, 1u,
                               __ATOMIC_ACQ_REL, __HIP_MEMORY_SCOPE_AGENT);
        lastFlag = (prev == HBLOCKS - 1) ? 1u : 0u;
    }
    __syncthreads();
    if (lastFlag == 0) return;

    // ---- final reduction (one block) ----
    // Agent-scope loads defeat stale per-XCD L2 lines.
    double hs = 0.0;
    for (int i = threadIdx.x; i < HBLOCKS; i += HTHREADS)
        hs += (double)__hip_atomic_load(&hpart[i], __ATOMIC_RELAXED,
                                        __HIP_MEMORY_SCOPE_AGENT);
    __shared__ double dsm[HTHREADS];
    dsm[threadIdx.x] = hs;

    __shared__ float rsm[7 * RBLOCKS];
    if (threadIdx.x < 7 * RBLOCKS)
        rsm[threadIdx.x] = __hip_atomic_load(&rpart[threadIdx.x],
                                             __ATOMIC_RELAXED,
                                             __HIP_MEMORY_SCOPE_AGENT);
    __syncthreads();
    for (int o = HTHREADS / 2; o > 0; o >>= 1) {
        if (threadIdx.x < o) dsm[threadIdx.x] += dsm[threadIdx.x + o];
        __syncthreads();
    }

    if (threadIdx.x == 0) {
        double huber_total = dsm[0];
        double acc[7];
        for (int c = 0; c < 7; c++) acc[c] = 0.0;
        for (int blk = 0; blk < RBLOCKS; blk++)
            for (int c = 0; c < 7; c++)
                acc[c] += (double)rsm[7 * blk + c];

        double amps_sum  = acc[0];
        double bw_sum    = acc[1];
        double ap_sum    = acc[2];
        double peaks_sum = acc[3];
        double mask_sum  = acc[4];
        double um_cnt    = acc[5];
        double um_amps   = acc[6];

        double l_recon  = huber_total / ((double)BATCH * FBINS);
        double l_sparse = amps_sum / ((double)BATCH * KSLOTS);
        double l_bw     = bw_sum / ((double)BATCH * KSLOTS);
        double l_ap     = ap_sum / (double)BATCH;
        double n_real   = mask_sum > 1.0 ? mask_sum : 1.0;
        double l_peaks  = peaks_sum / n_real;
        double n_um     = um_cnt > 1.0 ? um_cnt : 1.0;
        double l_um     = um_amps / n_um;

        double total = l_recon + (double)LS * l_sparse + (double)LBW * l_bw
                     + (double)LAP * l_ap + (double)LPK * l_peaks + (double)LUM * l_um;
        out[0] = (float)total;
    }
}

extern "C" void kernel_launch(void* const* d_in, const int* in_sizes, int n_in,
                              void* d_out, int out_size, void* d_ws, size_t ws_size,
                              hipStream_t stream) {
    const float* pred_psd = (const float*)d_in[0];
    const float* true_psd = (const float*)d_in[1];
    const float* cfs      = (const float*)d_in[2];
    const float* amps     = (const float*)d_in[3];
    const float* bws      = (const float*)d_in[4];
    const float* expn     = (const float*)d_in[5];
    const float* offs     = (const float*)d_in[6];
    const float* gt_cfs   = (const float*)d_in[7];
    const float* gt_amps  = (const float*)d_in[8];
    const float* gt_bws   = (const float*)d_in[9];
    const float* gt_off   = (const float*)d_in[10];
    const float* gt_exp   = (const float*)d_in[11];
    const float* mask     = (const float*)d_in[12];
    float* out = (float*)d_out;

    // ws layout: [0..63] counter (+pad), then hpart, then rpart
    unsigned int* counter = (unsigned int*)d_ws;
    float* hpart = (float*)d_ws + 64;
    float* rpart = hpart + HBLOCKS;

    hipMemsetAsync(counter, 0, sizeof(unsigned int), stream);
    row_partial<<<RBLOCKS, RTHREADS, 0, stream>>>(cfs, amps, bws, expn, offs,
                                                  gt_cfs, gt_amps, gt_bws,
                                                  gt_off, gt_exp, mask, rpart);
    huber_main<<<HBLOCKS, HTHREADS, 0, stream>>>(pred_psd, true_psd, hpart,
                                                 rpart, counter, out);
}

// Round 5
// 33.136 us; speedup vs baseline: 8.2100x; 8.2100x over previous
//
#include <hip/hip_runtime.h>

#define BATCH   8192
#define FBINS   2048
#define KSLOTS  6

#define HBLOCKS 4096
#define HTHREADS 256
#define HSTRIDE (HBLOCKS * HTHREADS)     // 1048576 float4 per sweep
#define HITERS  4                         // 4 sweeps: 4194304 float4 total

#define RTHREADS 256
#define RBLOCKS (BATCH / RTHREADS)        // 32
#define TOTBLOCKS (HBLOCKS + RBLOCKS)     // 4128

#define LS   0.1f
#define LBW  0.05f
#define BWMAX 4.0f
#define LAP  0.5f
#define LPK  0.3f
#define LUM  0.1f

// Keep-alive: input-only scalar constraints (tied 128-bit "+v" tuples are
// unsupported by the gfx950 inline-asm path — R3 compile failure).
#define KEEP4(v) asm volatile("" :: "v"((v).x), "v"((v).y), "v"((v).z), "v"((v).w))

__device__ __forceinline__ float huber4(float4 a, float4 b) {
    float s = 0.f;
    { float e = a.x - b.x; float ab = fabsf(e); s += (ab < 1.f) ? 0.5f * e * e : ab - 0.5f; }
    { float e = a.y - b.y; float ab = fabsf(e); s += (ab < 1.f) ? 0.5f * e * e : ab - 0.5f; }
    { float e = a.z - b.z; float ab = fabsf(e); s += (ab < 1.f) ? 0.5f * e * e : ab - 0.5f; }
    { float e = a.w - b.w; float ab = fabsf(e); s += (ab < 1.f) ? 0.5f * e * e : ab - 0.5f; }
    return s;
}

// ---------------- Kernel 1: huber partials (blocks 0..HBLOCKS-1)
//                  + row partials  (blocks HBLOCKS..HBLOCKS+RBLOCKS-1) ----------------
// rpart layout: rpart[7 * rb + c]:
//   0 amps_sum, 1 bw_sum, 2 ap_sum, 3 peaks_sum, 4 mask_sum, 5 um_cnt, 6 um_amps
__global__ __launch_bounds__(HTHREADS) void fused_partial(
    const float* __restrict__ pred,  const float* __restrict__ tgt,
    const float* __restrict__ cfs,   const float* __restrict__ amps,
    const float* __restrict__ bws,   const float* __restrict__ expn,
    const float* __restrict__ offs,  const float* __restrict__ gt_cfs,
    const float* __restrict__ gt_amps, const float* __restrict__ gt_bws,
    const float* __restrict__ gt_off, const float* __restrict__ gt_exp,
    const float* __restrict__ mask,
    float* __restrict__ hpart, float* __restrict__ rpart)
{
    __shared__ float sm[7][HTHREADS];

    if (blockIdx.x < HBLOCKS) {
        // ---------- Huber path ----------
        const int tid0 = blockIdx.x * HTHREADS + threadIdx.x;
        const float4* __restrict__ p4 = (const float4*)pred;
        const float4* __restrict__ t4 = (const float4*)tgt;

        float4 a0 = p4[tid0];
        float4 b0 = t4[tid0];
        float4 a1 = p4[tid0 + HSTRIDE];
        float4 b1 = t4[tid0 + HSTRIDE];
        float4 a2 = p4[tid0 + 2 * HSTRIDE];
        float4 b2 = t4[tid0 + 2 * HSTRIDE];
        float4 a3 = p4[tid0 + 3 * HSTRIDE];
        float4 b3 = t4[tid0 + 3 * HSTRIDE];
        // All 8 float4 must be materialized here -> 8 loads in flight.
        KEEP4(a0); KEEP4(b0); KEEP4(a1); KEEP4(b1);
        KEEP4(a2); KEEP4(b2); KEEP4(a3); KEEP4(b3);

        float s = huber4(a0, b0);
        s += huber4(a1, b1);
        s += huber4(a2, b2);
        s += huber4(a3, b3);

        #pragma unroll
        for (int o = 32; o > 0; o >>= 1)
            s += __shfl_down(s, o, 64);

        int wave = threadIdx.x >> 6;
        int lane = threadIdx.x & 63;
        if (lane == 0) sm[0][wave] = s;
        __syncthreads();
        if (threadIdx.x == 0)
            hpart[blockIdx.x] = sm[0][0] + sm[0][1] + sm[0][2] + sm[0][3];
        return;
    }

    // ---------- Row-matching path ----------
    const int rb = blockIdx.x - HBLOCKS;
    const int b = rb * HTHREADS + threadIdx.x;

    float amps_sum = 0.f, bw_sum = 0.f, ap_sum = 0.f, peaks_sum = 0.f;
    float mask_sum = 0.f, um_cnt = 0.f, um_amps = 0.f;

    {
        float c[KSLOTS], a[KSLOTS], w[KSLOTS];
        float gc[KSLOTS], ga[KSLOTS], gw[KSLOTS], m[KSLOTS];
        #pragma unroll
        for (int i = 0; i < KSLOTS; i++) {
            c[i]  = cfs[b * KSLOTS + i];
            a[i]  = amps[b * KSLOTS + i];
            w[i]  = bws[b * KSLOTS + i];
            gc[i] = gt_cfs[b * KSLOTS + i];
            ga[i] = gt_amps[b * KSLOTS + i];
            gw[i] = gt_bws[b * KSLOTS + i];
            m[i]  = mask[b * KSLOTS + i];
        }

        bool used[KSLOTS];
        #pragma unroll
        for (int i = 0; i < KSLOTS; i++) used[i] = false;

        // Sequential greedy over GT slots (lax.scan order); strict < = first-min
        // tie-break, matching jnp.argmin.
        for (int j = 0; j < KSLOTS; j++) {
            if (m[j] > 0.5f) {
                int best = -1;
                float bd = 3.402823e+38f;
                #pragma unroll
                for (int i = 0; i < KSLOTS; i++) {
                    if (!used[i]) {
                        float d = fabsf(gc[j] - c[i]);
                        if (d < bd) { bd = d; best = i; }
                    }
                }
                used[best] = true;
                float dc = c[best] - gc[j];
                float da = a[best] - ga[j];
                float dw = w[best] - gw[j];
                peaks_sum += dc * dc + da * da + dw * dw;
                mask_sum  += 1.f;
            }
        }

        #pragma unroll
        for (int i = 0; i < KSLOTS; i++) {
            amps_sum += a[i];
            float ex = fmaxf(w[i] - BWMAX, 0.f);
            bw_sum += ex * ex;
            if (!used[i]) { um_cnt += 1.f; um_amps += a[i]; }
        }

        float de = expn[b] - gt_exp[b];
        float dof = offs[b] - gt_off[b];
        ap_sum = de * de + dof * dof;
    }

    sm[0][threadIdx.x] = amps_sum;
    sm[1][threadIdx.x] = bw_sum;
    sm[2][threadIdx.x] = ap_sum;
    sm[3][threadIdx.x] = peaks_sum;
    sm[4][threadIdx.x] = mask_sum;
    sm[5][threadIdx.x] = um_cnt;
    sm[6][threadIdx.x] = um_amps;
    __syncthreads();
    for (int o = HTHREADS / 2; o > 0; o >>= 1) {
        if (threadIdx.x < o) {
            #pragma unroll
            for (int cidx = 0; cidx < 7; cidx++)
                sm[cidx][threadIdx.x] += sm[cidx][threadIdx.x + o];
        }
        __syncthreads();
    }
    if (threadIdx.x < 7) rpart[7 * rb + threadIdx.x] = sm[threadIdx.x][0];
}

// ---------------- Kernel 2: finalize (1 block) ----------------
__global__ __launch_bounds__(256) void finalize(
    const float* __restrict__ hpart, const float* __restrict__ rpart,
    float* __restrict__ out)
{
    __shared__ double sm[256];
    double s = 0.0;
    #pragma unroll
    for (int r = 0; r < HBLOCKS / 256; r++)
        s += (double)hpart[r * 256 + threadIdx.x];
    sm[threadIdx.x] = s;
    __syncthreads();
    for (int o = 128; o > 0; o >>= 1) {
        if (threadIdx.x < o) sm[threadIdx.x] += sm[threadIdx.x + o];
        __syncthreads();
    }

    if (threadIdx.x == 0) {
        double huber_total = sm[0];
        double acc[7];
        for (int c = 0; c < 7; c++) acc[c] = 0.0;
        for (int blk = 0; blk < RBLOCKS; blk++)
            for (int c = 0; c < 7; c++)
                acc[c] += (double)rpart[7 * blk + c];

        double amps_sum  = acc[0];
        double bw_sum    = acc[1];
        double ap_sum    = acc[2];
        double peaks_sum = acc[3];
        double mask_sum  = acc[4];
        double um_cnt    = acc[5];
        double um_amps   = acc[6];

        double l_recon  = huber_total / ((double)BATCH * FBINS);
        double l_sparse = amps_sum / ((double)BATCH * KSLOTS);
        double l_bw     = bw_sum / ((double)BATCH * KSLOTS);
        double l_ap     = ap_sum / (double)BATCH;
        double n_real   = mask_sum > 1.0 ? mask_sum : 1.0;
        double l_peaks  = peaks_sum / n_real;
        double n_um     = um_cnt > 1.0 ? um_cnt : 1.0;
        double l_um     = um_amps / n_um;

        double total = l_recon + (double)LS * l_sparse + (double)LBW * l_bw
                     + (double)LAP * l_ap + (double)LPK * l_peaks + (double)LUM * l_um;
        out[0] = (float)total;
    }
}

extern "C" void kernel_launch(void* const* d_in, const int* in_sizes, int n_in,
                              void* d_out, int out_size, void* d_ws, size_t ws_size,
                              hipStream_t stream) {
    const float* pred_psd = (const float*)d_in[0];
    const float* true_psd = (const float*)d_in[1];
    const float* cfs      = (const float*)d_in[2];
    const float* amps     = (const float*)d_in[3];
    const float* bws      = (const float*)d_in[4];
    const float* expn     = (const float*)d_in[5];
    const float* offs     = (const float*)d_in[6];
    const float* gt_cfs   = (const float*)d_in[7];
    const float* gt_amps  = (const float*)d_in[8];
    const float* gt_bws   = (const float*)d_in[9];
    const float* gt_off   = (const float*)d_in[10];
    const float* gt_exp   = (const float*)d_in[11];
    const float* mask     = (const float*)d_in[12];
    float* out = (float*)d_out;

    float* hpart = (float*)d_ws;                 // HBLOCKS floats
    float* rpart = hpart + HBLOCKS;              // 7*RBLOCKS floats

    fused_partial<<<TOTBLOCKS, HTHREADS, 0, stream>>>(
        pred_psd, true_psd, cfs, amps, bws, expn, offs,
        gt_cfs, gt_amps, gt_bws, gt_off, gt_exp, mask, hpart, rpart);
    finalize<<<1, 256, 0, stream>>>(hpart, rpart, out);
}

// Round 6
// 32.908 us; speedup vs baseline: 8.2672x; 1.0070x over previous
//
#include <hip/hip_runtime.h>

#define BATCH   8192
#define FBINS   2048
#define KSLOTS  6

#define HBLOCKS 2048
#define HTHREADS 256
#define NTHREADS (HBLOCKS * HTHREADS)    // 524288
#define HSTRIDE  NTHREADS                // float4 stride per sweep
// per-thread: 8 float4-pairs, two batches of 4 pairs (8 loads each)
// total float4 = 2048*256*8 = 4194304 = BATCH*FBINS/4

#define RBLOCKS (BATCH / HTHREADS)        // 32
#define TOTBLOCKS (HBLOCKS + RBLOCKS)     // 2080

#define LS   0.1f
#define LBW  0.05f
#define BWMAX 4.0f
#define LAP  0.5f
#define LPK  0.3f
#define LUM  0.1f

__device__ __forceinline__ float huber4(float4 a, float4 b) {
    float s = 0.f;
    { float e = a.x - b.x; float ab = fabsf(e); s += (ab < 1.f) ? 0.5f * e * e : ab - 0.5f; }
    { float e = a.y - b.y; float ab = fabsf(e); s += (ab < 1.f) ? 0.5f * e * e : ab - 0.5f; }
    { float e = a.z - b.z; float ab = fabsf(e); s += (ab < 1.f) ? 0.5f * e * e : ab - 0.5f; }
    { float e = a.w - b.w; float ab = fabsf(e); s += (ab < 1.f) ? 0.5f * e * e : ab - 0.5f; }
    return s;
}

// One batch: 8 float4 loads issued back-to-back, ONE asm keep-alive pinning
// all 8 (referencing .x of each pins the whole dwordx4 result), then compute.
__device__ __forceinline__ float huber_batch(const float4* __restrict__ p4,
                                             const float4* __restrict__ t4,
                                             int base) {
    float4 a0 = p4[base];
    float4 b0 = t4[base];
    float4 a1 = p4[base + HSTRIDE];
    float4 b1 = t4[base + HSTRIDE];
    float4 a2 = p4[base + 2 * HSTRIDE];
    float4 b2 = t4[base + 2 * HSTRIDE];
    float4 a3 = p4[base + 3 * HSTRIDE];
    float4 b3 = t4[base + 3 * HSTRIDE];
    asm volatile("" :: "v"(a0.x), "v"(b0.x), "v"(a1.x), "v"(b1.x),
                       "v"(a2.x), "v"(b2.x), "v"(a3.x), "v"(b3.x));
    float s = huber4(a0, b0);
    s += huber4(a1, b1);
    s += huber4(a2, b2);
    s += huber4(a3, b3);
    return s;
}

// ---------------- Kernel 1: huber partials + row partials ----------------
// rpart layout: rpart[7 * rb + c]:
//   0 amps_sum, 1 bw_sum, 2 ap_sum, 3 peaks_sum, 4 mask_sum, 5 um_cnt, 6 um_amps
__global__ __launch_bounds__(HTHREADS) void fused_partial(
    const float* __restrict__ pred,  const float* __restrict__ tgt,
    const float* __restrict__ cfs,   const float* __restrict__ amps,
    const float* __restrict__ bws,   const float* __restrict__ expn,
    const float* __restrict__ offs,  const float* __restrict__ gt_cfs,
    const float* __restrict__ gt_amps, const float* __restrict__ gt_bws,
    const float* __restrict__ gt_off, const float* __restrict__ gt_exp,
    const float* __restrict__ mask,
    float* __restrict__ hpart, float* __restrict__ rpart)
{
    __shared__ float sm[7][HTHREADS];

    if (blockIdx.x < HBLOCKS) {
        // ---------- Huber path ----------
        const int tid0 = blockIdx.x * HTHREADS + threadIdx.x;
        const float4* __restrict__ p4 = (const float4*)pred;
        const float4* __restrict__ t4 = (const float4*)tgt;

        float s = huber_batch(p4, t4, tid0);
        s += huber_batch(p4, t4, tid0 + 4 * HSTRIDE);

        #pragma unroll
        for (int o = 32; o > 0; o >>= 1)
            s += __shfl_down(s, o, 64);

        int wave = threadIdx.x >> 6;
        int lane = threadIdx.x & 63;
        if (lane == 0) sm[0][wave] = s;
        __syncthreads();
        if (threadIdx.x == 0)
            hpart[blockIdx.x] = sm[0][0] + sm[0][1] + sm[0][2] + sm[0][3];
        return;
    }

    // ---------- Row-matching path ----------
    const int rb = blockIdx.x - HBLOCKS;
    const int b = rb * HTHREADS + threadIdx.x;

    float amps_sum = 0.f, bw_sum = 0.f, ap_sum = 0.f, peaks_sum = 0.f;
    float mask_sum = 0.f, um_cnt = 0.f, um_amps = 0.f;

    {
        float c[KSLOTS], a[KSLOTS], w[KSLOTS];
        float gc[KSLOTS], ga[KSLOTS], gw[KSLOTS], m[KSLOTS];
        #pragma unroll
        for (int i = 0; i < KSLOTS; i++) {
            c[i]  = cfs[b * KSLOTS + i];
            a[i]  = amps[b * KSLOTS + i];
            w[i]  = bws[b * KSLOTS + i];
            gc[i] = gt_cfs[b * KSLOTS + i];
            ga[i] = gt_amps[b * KSLOTS + i];
            gw[i] = gt_bws[b * KSLOTS + i];
            m[i]  = mask[b * KSLOTS + i];
        }

        bool used[KSLOTS];
        #pragma unroll
        for (int i = 0; i < KSLOTS; i++) used[i] = false;

        // Sequential greedy over GT slots (lax.scan order); strict < = first-min
        // tie-break, matching jnp.argmin.
        for (int j = 0; j < KSLOTS; j++) {
            if (m[j] > 0.5f) {
                int best = -1;
                float bd = 3.402823e+38f;
                #pragma unroll
                for (int i = 0; i < KSLOTS; i++) {
                    if (!used[i]) {
                        float d = fabsf(gc[j] - c[i]);
                        if (d < bd) { bd = d; best = i; }
                    }
                }
                used[best] = true;
                float dc = c[best] - gc[j];
                float da = a[best] - ga[j];
                float dw = w[best] - gw[j];
                peaks_sum += dc * dc + da * da + dw * dw;
                mask_sum  += 1.f;
            }
        }

        #pragma unroll
        for (int i = 0; i < KSLOTS; i++) {
            amps_sum += a[i];
            float ex = fmaxf(w[i] - BWMAX, 0.f);
            bw_sum += ex * ex;
            if (!used[i]) { um_cnt += 1.f; um_amps += a[i]; }
        }

        float de = expn[b] - gt_exp[b];
        float dof = offs[b] - gt_off[b];
        ap_sum = de * de + dof * dof;
    }

    sm[0][threadIdx.x] = amps_sum;
    sm[1][threadIdx.x] = bw_sum;
    sm[2][threadIdx.x] = ap_sum;
    sm[3][threadIdx.x] = peaks_sum;
    sm[4][threadIdx.x] = mask_sum;
    sm[5][threadIdx.x] = um_cnt;
    sm[6][threadIdx.x] = um_amps;
    __syncthreads();
    for (int o = HTHREADS / 2; o > 0; o >>= 1) {
        if (threadIdx.x < o) {
            #pragma unroll
            for (int cidx = 0; cidx < 7; cidx++)
                sm[cidx][threadIdx.x] += sm[cidx][threadIdx.x + o];
        }
        __syncthreads();
    }
    if (threadIdx.x < 7) rpart[7 * rb + threadIdx.x] = sm[threadIdx.x][0];
}

// ---------------- Kernel 2: finalize (1 block) ----------------
__global__ __launch_bounds__(256) void finalize(
    const float* __restrict__ hpart, const float* __restrict__ rpart,
    float* __restrict__ out)
{
    __shared__ double sm[256];
    double s = 0.0;
    #pragma unroll
    for (int r = 0; r < HBLOCKS / 256; r++)
        s += (double)hpart[r * 256 + threadIdx.x];
    sm[threadIdx.x] = s;
    __syncthreads();
    for (int o = 128; o > 0; o >>= 1) {
        if (threadIdx.x < o) sm[threadIdx.x] += sm[threadIdx.x + o];
        __syncthreads();
    }

    if (threadIdx.x == 0) {
        double huber_total = sm[0];
        double acc[7];
        for (int c = 0; c < 7; c++) acc[c] = 0.0;
        for (int blk = 0; blk < RBLOCKS; blk++)
            for (int c = 0; c < 7; c++)
                acc[c] += (double)rpart[7 * blk + c];

        double amps_sum  = acc[0];
        double bw_sum    = acc[1];
        double ap_sum    = acc[2];
        double peaks_sum = acc[3];
        double mask_sum  = acc[4];
        double um_cnt    = acc[5];
        double um_amps   = acc[6];

        double l_recon  = huber_total / ((double)BATCH * FBINS);
        double l_sparse = amps_sum / ((double)BATCH * KSLOTS);
        double l_bw     = bw_sum / ((double)BATCH * KSLOTS);
        double l_ap     = ap_sum / (double)BATCH;
        double n_real   = mask_sum > 1.0 ? mask_sum : 1.0;
        double l_peaks  = peaks_sum / n_real;
        double n_um     = um_cnt > 1.0 ? um_cnt : 1.0;
        double l_um     = um_amps / n_um;

        double total = l_recon + (double)LS * l_sparse + (double)LBW * l_bw
                     + (double)LAP * l_ap + (double)LPK * l_peaks + (double)LUM * l_um;
        out[0] = (float)total;
    }
}

extern "C" void kernel_launch(void* const* d_in, const int* in_sizes, int n_in,
                              void* d_out, int out_size, void* d_ws, size_t ws_size,
                              hipStream_t stream) {
    const float* pred_psd = (const float*)d_in[0];
    const float* true_psd = (const float*)d_in[1];
    const float* cfs      = (const float*)d_in[2];
    const float* amps     = (const float*)d_in[3];
    const float* bws      = (const float*)d_in[4];
    const float* expn     = (const float*)d_in[5];
    const float* offs     = (const float*)d_in[6];
    const float* gt_cfs   = (const float*)d_in[7];
    const float* gt_amps  = (const float*)d_in[8];
    const float* gt_bws   = (const float*)d_in[9];
    const float* gt_off   = (const float*)d_in[10];
    const float* gt_exp   = (const float*)d_in[11];
    const float* mask     = (const float*)d_in[12];
    float* out = (float*)d_out;

    float* hpart = (float*)d_ws;                 // HBLOCKS floats
    float* rpart = hpart + HBLOCKS;              // 7*RBLOCKS floats

    fused_partial<<<TOTBLOCKS, HTHREADS, 0, stream>>>(
        pred_psd, true_psd, cfs, amps, bws, expn, offs,
        gt_cfs, gt_amps, gt_bws, gt_off, gt_exp, mask, hpart, rpart);
    finalize<<<1, 256, 0, stream>>>(hpart, rpart, out);
}

// Round 7
// 30.978 us; speedup vs baseline: 8.7821x; 1.0623x over previous
//
#include <hip/hip_runtime.h>

#define BATCH   8192
#define FBINS   2048
#define KSLOTS  6

#define HTHREADS 512
#define HWAVES   (HTHREADS / 64)          // 8
#define HBLOCKS  2048
#define BLK_F4   2048                     // float4 per array per block (32 KB)
#define WAVE_F4  (BLK_F4 / HWAVES)        // 256 float4 per wave per array
#define SPT      4                        // DMA stages per wave per array (64 f4 each)
// total: 2048 blocks * 2048 float4 = 4194304 = BATCH*FBINS/4  ✓

#define RBLOCKS   (BATCH / HTHREADS)      // 16
#define TOTBLOCKS (HBLOCKS + RBLOCKS)     // 2064

#define LS   0.1f
#define LBW  0.05f
#define BWMAX 4.0f
#define LAP  0.5f
#define LPK  0.3f
#define LUM  0.1f

__device__ __forceinline__ void gload16(const void* g, void* l) {
    // async global->LDS DMA, 16 B per lane; LDS dest = wave-uniform base + lane*16
    __builtin_amdgcn_global_load_lds(
        (const __attribute__((address_space(1))) void*)g,
        (__attribute__((address_space(3))) void*)l, 16, 0, 0);
}

__device__ __forceinline__ float huber4(float4 a, float4 b) {
    float s = 0.f;
    { float e = a.x - b.x; float ab = fabsf(e); s += (ab < 1.f) ? 0.5f * e * e : ab - 0.5f; }
    { float e = a.y - b.y; float ab = fabsf(e); s += (ab < 1.f) ? 0.5f * e * e : ab - 0.5f; }
    { float e = a.z - b.z; float ab = fabsf(e); s += (ab < 1.f) ? 0.5f * e * e : ab - 0.5f; }
    { float e = a.w - b.w; float ab = fabsf(e); s += (ab < 1.f) ? 0.5f * e * e : ab - 0.5f; }
    return s;
}

// ---------------- Kernel 1: huber partials (DMA-staged) + row partials ----------------
// rpart layout: rpart[7 * rb + c]:
//   0 amps_sum, 1 bw_sum, 2 ap_sum, 3 peaks_sum, 4 mask_sum, 5 um_cnt, 6 um_amps
__global__ __launch_bounds__(HTHREADS) void fused_partial(
    const float* __restrict__ pred,  const float* __restrict__ tgt,
    const float* __restrict__ cfs,   const float* __restrict__ amps,
    const float* __restrict__ bws,   const float* __restrict__ expn,
    const float* __restrict__ offs,  const float* __restrict__ gt_cfs,
    const float* __restrict__ gt_amps, const float* __restrict__ gt_bws,
    const float* __restrict__ gt_off, const float* __restrict__ gt_exp,
    const float* __restrict__ mask,
    float* __restrict__ hpart, float* __restrict__ rpart)
{
    __shared__ float4 ldsA[BLK_F4];     // 32 KB
    __shared__ float4 ldsB[BLK_F4];     // 32 KB
    __shared__ float  wred[HWAVES][8];  // wave partials (8th col pads)

    const int tid  = threadIdx.x;
    const int wave = tid >> 6;
    const int lane = tid & 63;

    if (blockIdx.x < HBLOCKS) {
        // ---------- Huber path ----------
        const float4* __restrict__ a4 = (const float4*)pred;
        const float4* __restrict__ b4 = (const float4*)tgt;
        const int wbase = wave * WAVE_F4;
        const long long gbase = (long long)blockIdx.x * BLK_F4 + wbase;

        // 8 DMA issues back-to-back: 8 KB in flight per wave, no VGPR round-trip.
        #pragma unroll
        for (int s = 0; s < SPT; s++)
            gload16(&a4[gbase + s * 64 + lane], &ldsA[wbase + s * 64]);
        #pragma unroll
        for (int s = 0; s < SPT; s++)
            gload16(&b4[gbase + s * 64 + lane], &ldsB[wbase + s * 64]);
        asm volatile("s_waitcnt vmcnt(0)" ::: "memory");

        // read back exactly in the written lane*16B order: conflict-free b128
        float ssum = 0.f;
        #pragma unroll
        for (int s = 0; s < SPT; s++) {
            float4 a = ldsA[wbase + s * 64 + lane];
            float4 b = ldsB[wbase + s * 64 + lane];
            ssum += huber4(a, b);
        }

        #pragma unroll
        for (int o = 32; o > 0; o >>= 1)
            ssum += __shfl_down(ssum, o, 64);
        if (lane == 0) wred[wave][0] = ssum;
        __syncthreads();
        if (tid == 0) {
            float t = 0.f;
            #pragma unroll
            for (int w = 0; w < HWAVES; w++) t += wred[w][0];
            hpart[blockIdx.x] = t;
        }
        return;
    }

    // ---------- Row-matching path ----------
    const int rb = blockIdx.x - HBLOCKS;
    const int b = rb * HTHREADS + tid;

    float acc[7];   // amps, bw, ap, peaks, mask, um_cnt, um_amps
    #pragma unroll
    for (int c = 0; c < 7; c++) acc[c] = 0.f;

    {
        float c[KSLOTS], a[KSLOTS], w[KSLOTS];
        float gc[KSLOTS], ga[KSLOTS], gw[KSLOTS], m[KSLOTS];
        #pragma unroll
        for (int i = 0; i < KSLOTS; i++) {
            c[i]  = cfs[b * KSLOTS + i];
            a[i]  = amps[b * KSLOTS + i];
            w[i]  = bws[b * KSLOTS + i];
            gc[i] = gt_cfs[b * KSLOTS + i];
            ga[i] = gt_amps[b * KSLOTS + i];
            gw[i] = gt_bws[b * KSLOTS + i];
            m[i]  = mask[b * KSLOTS + i];
        }

        bool used[KSLOTS];
        #pragma unroll
        for (int i = 0; i < KSLOTS; i++) used[i] = false;

        // Sequential greedy over GT slots (lax.scan order); strict < = first-min
        // tie-break, matching jnp.argmin.
        for (int j = 0; j < KSLOTS; j++) {
            if (m[j] > 0.5f) {
                int best = -1;
                float bd = 3.402823e+38f;
                #pragma unroll
                for (int i = 0; i < KSLOTS; i++) {
                    if (!used[i]) {
                        float d = fabsf(gc[j] - c[i]);
                        if (d < bd) { bd = d; best = i; }
                    }
                }
                used[best] = true;
                float dc = c[best] - gc[j];
                float da = a[best] - ga[j];
                float dw = w[best] - gw[j];
                acc[3] += dc * dc + da * da + dw * dw;
                acc[4] += 1.f;
            }
        }

        #pragma unroll
        for (int i = 0; i < KSLOTS; i++) {
            acc[0] += a[i];
            float ex = fmaxf(w[i] - BWMAX, 0.f);
            acc[1] += ex * ex;
            if (!used[i]) { acc[5] += 1.f; acc[6] += a[i]; }
        }

        float de = expn[b] - gt_exp[b];
        float dof = offs[b] - gt_off[b];
        acc[2] = de * de + dof * dof;
    }

    // wave shuffle-reduce each of the 7 sums, then cross-wave via LDS
    #pragma unroll
    for (int c = 0; c < 7; c++) {
        float v = acc[c];
        #pragma unroll
        for (int o = 32; o > 0; o >>= 1)
            v += __shfl_down(v, o, 64);
        acc[c] = v;
    }
    if (lane == 0) {
        #pragma unroll
        for (int c = 0; c < 7; c++) wred[wave][c] = acc[c];
    }
    __syncthreads();
    if (tid < 7) {
        float t = 0.f;
        #pragma unroll
        for (int w = 0; w < HWAVES; w++) t += wred[w][tid];
        rpart[7 * rb + tid] = t;
    }
}

// ---------------- Kernel 2: finalize (1 block) ----------------
__global__ __launch_bounds__(256) void finalize(
    const float* __restrict__ hpart, const float* __restrict__ rpart,
    float* __restrict__ out)
{
    __shared__ double sm[256];
    double s = 0.0;
    #pragma unroll
    for (int r = 0; r < HBLOCKS / 256; r++)
        s += (double)hpart[r * 256 + threadIdx.x];
    sm[threadIdx.x] = s;
    __syncthreads();
    for (int o = 128; o > 0; o >>= 1) {
        if (threadIdx.x < o) sm[threadIdx.x] += sm[threadIdx.x + o];
        __syncthreads();
    }

    if (threadIdx.x == 0) {
        double huber_total = sm[0];
        double acc[7];
        for (int c = 0; c < 7; c++) acc[c] = 0.0;
        for (int blk = 0; blk < RBLOCKS; blk++)
            for (int c = 0; c < 7; c++)
                acc[c] += (double)rpart[7 * blk + c];

        double l_recon  = huber_total / ((double)BATCH * FBINS);
        double l_sparse = acc[0] / ((double)BATCH * KSLOTS);
        double l_bw     = acc[1] / ((double)BATCH * KSLOTS);
        double l_ap     = acc[2] / (double)BATCH;
        double n_real   = acc[4] > 1.0 ? acc[4] : 1.0;
        double l_peaks  = acc[3] / n_real;
        double n_um     = acc[5] > 1.0 ? acc[5] : 1.0;
        double l_um     = acc[6] / n_um;

        double total = l_recon + (double)LS * l_sparse + (double)LBW * l_bw
                     + (double)LAP * l_ap + (double)LPK * l_peaks + (double)LUM * l_um;
        out[0] = (float)total;
    }
}

extern "C" void kernel_launch(void* const* d_in, const int* in_sizes, int n_in,
                              void* d_out, int out_size, void* d_ws, size_t ws_size,
                              hipStream_t stream) {
    const float* pred_psd = (const float*)d_in[0];
    const float* true_psd = (const float*)d_in[1];
    const float* cfs      = (const float*)d_in[2];
    const float* amps     = (const float*)d_in[3];
    const float* bws      = (const float*)d_in[4];
    const float* expn     = (const float*)d_in[5];
    const float* offs     = (const float*)d_in[6];
    const float* gt_cfs   = (const float*)d_in[7];
    const float* gt_amps  = (const float*)d_in[8];
    const float* gt_bws   = (const float*)d_in[9];
    const float* gt_off   = (const float*)d_in[10];
    const float* gt_exp   = (const float*)d_in[11];
    const float* mask     = (const float*)d_in[12];
    float* out = (float*)d_out;

    float* hpart = (float*)d_ws;                 // HBLOCKS floats
    float* rpart = hpart + HBLOCKS;              // 7*RBLOCKS floats

    fused_partial<<<TOTBLOCKS, HTHREADS, 0, stream>>>(
        pred_psd, true_psd, cfs, amps, bws, expn, offs,
        gt_cfs, gt_amps, gt_bws, gt_off, gt_exp, mask, hpart, rpart);
    finalize<<<1, 256, 0, stream>>>(hpart, rpart, out);
}

// Round 8
// 30.747 us; speedup vs baseline: 8.8480x; 1.0075x over previous
//
#include <hip/hip_runtime.h>

#define BATCH   8192
#define FBINS   2048
#define KSLOTS  6

#define HTHREADS 512
#define HWAVES   8
#define HBLOCKS  512
#define TILES    8
#define TILE_F4  1024                    // float4 per array per tile (16 KB)
#define WTILE_F4 (TILE_F4 / HWAVES)      // 128 per wave per array per tile
#define BLK_F4   (TILES * TILE_F4)       // 8192 per array per block
// HBLOCKS * BLK_F4 = 512*8192 = 4194304 = BATCH*FBINS/4  ✓

#define RBLOCKS   (BATCH / HTHREADS)     // 16
#define TOTBLOCKS (HBLOCKS + RBLOCKS)    // 528

#define LS   0.1f
#define LBW  0.05f
#define BWMAX 4.0f
#define LAP  0.5f
#define LPK  0.3f
#define LUM  0.1f

__device__ __forceinline__ void gload16(const float4* g, float4* l) {
    // async global->LDS DMA, 16 B/lane; global src per-lane, LDS dest wave-uniform
    __builtin_amdgcn_global_load_lds(
        (const __attribute__((address_space(1))) void*)g,
        (__attribute__((address_space(3))) void*)l, 16, 0, 0);
}

__device__ __forceinline__ float huber4(float4 a, float4 b) {
    float s = 0.f;
    { float e = a.x - b.x; float ab = fabsf(e); s += (ab < 1.f) ? 0.5f * e * e : ab - 0.5f; }
    { float e = a.y - b.y; float ab = fabsf(e); s += (ab < 1.f) ? 0.5f * e * e : ab - 0.5f; }
    { float e = a.z - b.z; float ab = fabsf(e); s += (ab < 1.f) ? 0.5f * e * e : ab - 0.5f; }
    { float e = a.w - b.w; float ab = fabsf(e); s += (ab < 1.f) ? 0.5f * e * e : ab - 0.5f; }
    return s;
}

// ---------------- Kernel 1: pipelined-DMA huber partials + row partials ----------------
// rpart layout: rpart[7 * rb + c]:
//   0 amps_sum, 1 bw_sum, 2 ap_sum, 3 peaks_sum, 4 mask_sum, 5 um_cnt, 6 um_amps
__global__ __launch_bounds__(HTHREADS) void fused_partial(
    const float* __restrict__ pred,  const float* __restrict__ tgt,
    const float* __restrict__ cfs,   const float* __restrict__ amps,
    const float* __restrict__ bws,   const float* __restrict__ expn,
    const float* __restrict__ offs,  const float* __restrict__ gt_cfs,
    const float* __restrict__ gt_amps, const float* __restrict__ gt_bws,
    const float* __restrict__ gt_off, const float* __restrict__ gt_exp,
    const float* __restrict__ mask,
    float* __restrict__ hpart, float* __restrict__ rpart)
{
    __shared__ float4 ldsA[2][TILE_F4];   // 32 KB
    __shared__ float4 ldsB[2][TILE_F4];   // 32 KB
    __shared__ float  wred[HWAVES][8];

    const int tid  = threadIdx.x;
    const int wave = tid >> 6;
    const int lane = tid & 63;

    if (blockIdx.x < HBLOCKS) {
        // ---------- Huber path: barrier-free per-wave DMA pipeline ----------
        const float4* __restrict__ a4 = (const float4*)pred;
        const float4* __restrict__ b4 = (const float4*)tgt;
        const int woff  = wave * WTILE_F4;            // wave-private LDS slice
        const int gbase = blockIdx.x * BLK_F4 + woff + lane;

        // prologue: issue tile 0 (4 DMAs per wave)
        {
            const float4* ga = a4 + gbase;
            const float4* gb = b4 + gbase;
            gload16(ga,      &ldsA[0][woff]);
            gload16(ga + 64, &ldsA[0][woff + 64]);
            gload16(gb,      &ldsB[0][woff]);
            gload16(gb + 64, &ldsB[0][woff + 64]);
        }

        float ssum = 0.f;
        #pragma unroll
        for (int t = 0; t < TILES; t++) {
            const int buf = t & 1;
            if (t + 1 < TILES) {
                // issue next tile into other buffer, then wait only for tile t
                const float4* ga = a4 + gbase + (t + 1) * TILE_F4;
                const float4* gb = b4 + gbase + (t + 1) * TILE_F4;
                gload16(ga,      &ldsA[buf ^ 1][woff]);
                gload16(ga + 64, &ldsA[buf ^ 1][woff + 64]);
                gload16(gb,      &ldsB[buf ^ 1][woff]);
                gload16(gb + 64, &ldsB[buf ^ 1][woff + 64]);
                asm volatile("s_waitcnt vmcnt(4)" ::: "memory");
            } else {
                asm volatile("s_waitcnt vmcnt(0)" ::: "memory");
            }
            __builtin_amdgcn_sched_barrier(0);

            // consume tile t from the wave-private slice (conflict-free b128)
            float4 a0 = ldsA[buf][woff + lane];
            float4 b0 = ldsB[buf][woff + lane];
            float4 a1 = ldsA[buf][woff + 64 + lane];
            float4 b1 = ldsB[buf][woff + 64 + lane];
            ssum += huber4(a0, b0);
            ssum += huber4(a1, b1);
        }

        #pragma unroll
        for (int o = 32; o > 0; o >>= 1)
            ssum += __shfl_down(ssum, o, 64);
        if (lane == 0) wred[wave][0] = ssum;
        __syncthreads();
        if (tid == 0) {
            float t = 0.f;
            #pragma unroll
            for (int w = 0; w < HWAVES; w++) t += wred[w][0];
            hpart[blockIdx.x] = t;
        }
        return;
    }

    // ---------- Row-matching path ----------
    const int rb = blockIdx.x - HBLOCKS;
    const int b = rb * HTHREADS + tid;

    float acc[7];   // amps, bw, ap, peaks, mask, um_cnt, um_amps
    #pragma unroll
    for (int c = 0; c < 7; c++) acc[c] = 0.f;

    {
        float c[KSLOTS], a[KSLOTS], w[KSLOTS];
        float gc[KSLOTS], ga[KSLOTS], gw[KSLOTS], m[KSLOTS];
        #pragma unroll
        for (int i = 0; i < KSLOTS; i++) {
            c[i]  = cfs[b * KSLOTS + i];
            a[i]  = amps[b * KSLOTS + i];
            w[i]  = bws[b * KSLOTS + i];
            gc[i] = gt_cfs[b * KSLOTS + i];
            ga[i] = gt_amps[b * KSLOTS + i];
            gw[i] = gt_bws[b * KSLOTS + i];
            m[i]  = mask[b * KSLOTS + i];
        }

        bool used[KSLOTS];
        #pragma unroll
        for (int i = 0; i < KSLOTS; i++) used[i] = false;

        // Sequential greedy over GT slots (lax.scan order); strict < = first-min
        // tie-break, matching jnp.argmin.
        for (int j = 0; j < KSLOTS; j++) {
            if (m[j] > 0.5f) {
                int best = -1;
                float bd = 3.402823e+38f;
                #pragma unroll
                for (int i = 0; i < KSLOTS; i++) {
                    if (!used[i]) {
                        float d = fabsf(gc[j] - c[i]);
                        if (d < bd) { bd = d; best = i; }
                    }
                }
                used[best] = true;
                float dc = c[best] - gc[j];
                float da = a[best] - ga[j];
                float dw = w[best] - gw[j];
                acc[3] += dc * dc + da * da + dw * dw;
                acc[4] += 1.f;
            }
        }

        #pragma unroll
        for (int i = 0; i < KSLOTS; i++) {
            acc[0] += a[i];
            float ex = fmaxf(w[i] - BWMAX, 0.f);
            acc[1] += ex * ex;
            if (!used[i]) { acc[5] += 1.f; acc[6] += a[i]; }
        }

        float de = expn[b] - gt_exp[b];
        float dof = offs[b] - gt_off[b];
        acc[2] = de * de + dof * dof;
    }

    #pragma unroll
    for (int c = 0; c < 7; c++) {
        float v = acc[c];
        #pragma unroll
        for (int o = 32; o > 0; o >>= 1)
            v += __shfl_down(v, o, 64);
        acc[c] = v;
    }
    if (lane == 0) {
        #pragma unroll
        for (int c = 0; c < 7; c++) wred[wave][c] = acc[c];
    }
    __syncthreads();
    if (tid < 7) {
        float t = 0.f;
        #pragma unroll
        for (int w = 0; w < HWAVES; w++) t += wred[w][tid];
        rpart[7 * rb + tid] = t;
    }
}

// ---------------- Kernel 2: finalize (1 block) ----------------
__global__ __launch_bounds__(256) void finalize(
    const float* __restrict__ hpart, const float* __restrict__ rpart,
    float* __restrict__ out)
{
    __shared__ double sm[256];
    double s = 0.0;
    #pragma unroll
    for (int r = 0; r < HBLOCKS / 256; r++)
        s += (double)hpart[r * 256 + threadIdx.x];
    sm[threadIdx.x] = s;
    __syncthreads();
    for (int o = 128; o > 0; o >>= 1) {
        if (threadIdx.x < o) sm[threadIdx.x] += sm[threadIdx.x + o];
        __syncthreads();
    }

    if (threadIdx.x == 0) {
        double huber_total = sm[0];
        double acc[7];
        for (int c = 0; c < 7; c++) acc[c] = 0.0;
        for (int blk = 0; blk < RBLOCKS; blk++)
            for (int c = 0; c < 7; c++)
                acc[c] += (double)rpart[7 * blk + c];

        double l_recon  = huber_total / ((double)BATCH * FBINS);
        double l_sparse = acc[0] / ((double)BATCH * KSLOTS);
        double l_bw     = acc[1] / ((double)BATCH * KSLOTS);
        double l_ap     = acc[2] / (double)BATCH;
        double n_real   = acc[4] > 1.0 ? acc[4] : 1.0;
        double l_peaks  = acc[3] / n_real;
        double n_um     = acc[5] > 1.0 ? acc[5] : 1.0;
        double l_um     = acc[6] / n_um;

        double total = l_recon + (double)LS * l_sparse + (double)LBW * l_bw
                     + (double)LAP * l_ap + (double)LPK * l_peaks + (double)LUM * l_um;
        out[0] = (float)total;
    }
}

extern "C" void kernel_launch(void* const* d_in, const int* in_sizes, int n_in,
                              void* d_out, int out_size, void* d_ws, size_t ws_size,
                              hipStream_t stream) {
    const float* pred_psd = (const float*)d_in[0];
    const float* true_psd = (const float*)d_in[1];
    const float* cfs      = (const float*)d_in[2];
    const float* amps     = (const float*)d_in[3];
    const float* bws      = (const float*)d_in[4];
    const float* expn     = (const float*)d_in[5];
    const float* offs     = (const float*)d_in[6];
    const float* gt_cfs   = (const float*)d_in[7];
    const float* gt_amps  = (const float*)d_in[8];
    const float* gt_bws   = (const float*)d_in[9];
    const float* gt_off   = (const float*)d_in[10];
    const float* gt_exp   = (const float*)d_in[11];
    const float* mask     = (const float*)d_in[12];
    float* out = (float*)d_out;

    float* hpart = (float*)d_ws;                 // HBLOCKS floats
    float* rpart = hpart + HBLOCKS;              // 7*RBLOCKS floats

    fused_partial<<<TOTBLOCKS, HTHREADS, 0, stream>>>(
        pred_psd, true_psd, cfs, amps, bws, expn, offs,
        gt_cfs, gt_amps, gt_bws, gt_off, gt_exp, mask, hpart, rpart);
    finalize<<<1, 256, 0, stream>>>(hpart, rpart, out);
}